// Round 8
// baseline (469.295 us; speedup 1.0000x reference)
//
#include <hip/hip_runtime.h>

// DiscreteMMSE, round 8: ws-robust NCHUNK selection + 4 waves/SIMD.
//
//   data   : [B=128][N=128][D=64] f32
//   targets: [B=128][N=128]       f32
//   W      : [D=64][T=4096]       f32
//   out    : [B=128][N=128]       f32
//
// K1<NCHUNK>: one WAVE per (batch, T/NCHUNK-col chunk). No barriers, no LDS.
//   Per step n the wave emits (m_ref, s, p) over its cols, m_ref = exact
//   chunk max of csum_{n-1} from the previous step's fused in-wave reduce.
//   csum starts 0 and decreases -> exp2 args <= 0; n=0 falls out (e=1).
// K2: per (b,n) online associative softmax combine over chunk partials.
//   Layout part[chunk][b*N+n] -> K2 loads lane-coalesced.
//
// Round-7 post-mortem: container died with no counters. Hypotheses: infra
// flake OR ws_size < 8 MB -> OOB partial writes -> GPU fault. This round
// defends: NCHUNK=32 (8 MB, 4096 waves = 4/SIMD) only if ws_size allows,
// else NCHUNK=16 (4 MB, proven in round 6). Branch depends only on ws_size
// (constant across calls) -> same work every call, graph-capture safe.
//
// Round-6 evidence for the occupancy theory: K1 210us, VALUBusy 54%,
// Occupancy 20% (2 waves/SIMD, grid-limited); GEMM issue floor ~55us.

#define B 128
#define N 128
#define D 64
#define T 4096
#define NT 16
#define NTILES (N / NT)
#define K1_BLK 256
#define K1_WPB (K1_BLK / 64)

// DPP ctrl codes
#define DPP_XOR1 0xB1    // quad_perm(1,0,3,2)
#define DPP_XOR2 0x4E    // quad_perm(2,3,0,1)
#define DPP_XOR4 0x141   // row_half_mirror
#define DPP_XOR8 0x140   // row_mirror

template <int CTRL>
__device__ __forceinline__ float dppf(float x) {
    return __int_as_float(
        __builtin_amdgcn_mov_dpp(__float_as_int(x), CTRL, 0xF, 0xF, true));
}

// full-wave (64-lane) reduce of (m:max, s:sum, p:sum); result in all lanes
__device__ __forceinline__ void wave_red3(float& m, float& s, float& p) {
    m = fmaxf(m, dppf<DPP_XOR1>(m)); s += dppf<DPP_XOR1>(s); p += dppf<DPP_XOR1>(p);
    m = fmaxf(m, dppf<DPP_XOR2>(m)); s += dppf<DPP_XOR2>(s); p += dppf<DPP_XOR2>(p);
    m = fmaxf(m, dppf<DPP_XOR4>(m)); s += dppf<DPP_XOR4>(s); p += dppf<DPP_XOR4>(p);
    m = fmaxf(m, dppf<DPP_XOR8>(m)); s += dppf<DPP_XOR8>(s); p += dppf<DPP_XOR8>(p);
    m = fmaxf(m, __shfl_xor(m, 16, 64)); s += __shfl_xor(s, 16, 64); p += __shfl_xor(p, 16, 64);
    m = fmaxf(m, __shfl_xor(m, 32, 64)); s += __shfl_xor(s, 32, 64); p += __shfl_xor(p, 32, 64);
}

template <int NCHUNK_>
__global__ __launch_bounds__(K1_BLK, 4)
void dmmse_k1(const float* __restrict__ data,
              const float* __restrict__ targets,
              const float* __restrict__ W,
              float4* __restrict__ part)      // [NCHUNK_][B*N] (m, s, p, _)
{
    constexpr int CPW = T / NCHUNK_;   // cols per wave
    constexpr int CPL = CPW / 64;      // cols per lane (2 or 4)
    constexpr int F2  = CPL / 2;       // float2 loads per lane per W row

    const int tid   = threadIdx.x;
    const int lane  = tid & 63;
    const int g     = blockIdx.x * K1_WPB + (tid >> 6);   // global wave id
    const int b     = g / NCHUNK_;                        // batch
    const int chunk = g % NCHUNK_;                        // col chunk

    const float2* W2 = reinterpret_cast<const float2*>(W);  // [D][T/2]
    int wcol[F2];
    #pragma unroll
    for (int f = 0; f < F2; ++f) wcol[f] = chunk * (CPW / 2) + f * 64 + lane;

    const float KHL2E = -0.5f * 1.44269504088896340736f;  // -0.5*log2(e)

    float csum[CPL];
    #pragma unroll
    for (int c = 0; c < CPL; ++c) csum[c] = 0.f;
    float M = 0.f;    // chunk max of csum_{n-1}; 0 at n==0

    for (int j = 0; j < NTILES; ++j) {
        // ---- mu[i][c] = data[n_i] . W[:, chunk cols] for this n-tile ----
        float mu[NT][CPL];
        #pragma unroll
        for (int i = 0; i < NT; ++i) {
            #pragma unroll
            for (int c = 0; c < CPL; ++c) mu[i][c] = 0.f;
        }

        const float* drow = data + (b * N + j * NT) * D;   // lane-uniform base

        // register double-buffered W stream over groups of 4 rows
        float2 a[4][F2], nb[4][F2];
        #pragma unroll
        for (int r = 0; r < 4; ++r) {
            #pragma unroll
            for (int f = 0; f < F2; ++f) a[r][f] = W2[r * (T / 2) + wcol[f]];
        }

        for (int dc = 0; dc < D; dc += 4) {
            if (dc < D - 4) {
                #pragma unroll
                for (int r = 0; r < 4; ++r) {
                    #pragma unroll
                    for (int f = 0; f < F2; ++f)
                        nb[r][f] = W2[(dc + 4 + r) * (T / 2) + wcol[f]];
                }
            }
            #pragma unroll
            for (int i = 0; i < NT; ++i) {
                // lane-uniform address -> scalar load, x in SGPRs
                const float4 x = *reinterpret_cast<const float4*>(drow + i * D + dc);
                const float xr[4] = {x.x, x.y, x.z, x.w};
                #pragma unroll
                for (int r = 0; r < 4; ++r) {
                    #pragma unroll
                    for (int f = 0; f < F2; ++f) {
                        mu[i][2 * f + 0] = fmaf(xr[r], a[r][f].x, mu[i][2 * f + 0]);
                        mu[i][2 * f + 1] = fmaf(xr[r], a[r][f].y, mu[i][2 * f + 1]);
                    }
                }
            }
            if (dc < D - 4) {
                #pragma unroll
                for (int r = 0; r < 4; ++r) {
                    #pragma unroll
                    for (int f = 0; f < F2; ++f) a[r][f] = nb[r][f];
                }
            }
        }

        // ---- sequential steps over the tile: pure in-wave reduce each ----
        #pragma unroll
        for (int i = 0; i < NT; ++i) {
            const int n = j * NT + i;

            // softmax weights vs csum_{n-1}, chunk-exact reference M
            float s = 0.f, p = 0.f;
            #pragma unroll
            for (int c = 0; c < CPL; ++c) {
                const float e = exp2f(csum[c] - M);
                s += e;
                p = fmaf(e, mu[i][c], p);
            }

            // accumulate log2-prob of point n (t-uniform constants dropped)
            if (n < N - 1) {
                const float y = targets[b * N + n];   // lane-uniform -> s_load
                #pragma unroll
                for (int c = 0; c < CPL; ++c) {
                    const float e = y - mu[i][c];
                    csum[c] = fmaf(KHL2E * e, e, csum[c]);
                }
            }
            float m = csum[0];
            #pragma unroll
            for (int c = 1; c < CPL; ++c) m = fmaxf(m, csum[c]);

            // fused in-wave reduce (DPP + 2 shfl levels), no barrier
            wave_red3(m, s, p);
            if (lane == 0)
                part[chunk * (B * N) + b * N + n] = make_float4(M, s, p, 0.f);
            M = m;   // exact chunk max of csum_n, reference for step n+1
        }
    }
}

__global__ __launch_bounds__(256)
void dmmse_k2(const float4* __restrict__ part,   // [nchunk][B*N]
              float* __restrict__ out,           // [B*N]
              int nchunk)
{
    const int t = blockIdx.x * 256 + threadIdx.x;   // (b*N + n), 0..16383

    // online associative softmax combine over chunks
    float M = -__builtin_inff(), S = 0.f, P = 0.f;
    for (int c = 0; c < nchunk; ++c) {
        const float4 v = part[c * (B * N) + t];     // lane-coalesced
        const float nM = fmaxf(M, v.x);
        const float aa = exp2f(M - nM);             // 0 on first iter
        const float f  = exp2f(v.x - nM);
        S = S * aa + v.y * f;
        P = P * aa + v.z * f;
        M = nM;
    }
    out[t] = P / S;
}

extern "C" void kernel_launch(void* const* d_in, const int* in_sizes, int n_in,
                              void* d_out, int out_size, void* d_ws, size_t ws_size,
                              hipStream_t stream)
{
    const float* data    = (const float*)d_in[0];   // 128*128*64
    const float* targets = (const float*)d_in[1];   // 128*128
    const float* W       = (const float*)d_in[2];   // 64*4096
    float* out           = (float*)d_out;           // 128*128
    float4* part         = (float4*)d_ws;

    const size_t need32 = (size_t)32 * B * N * sizeof(float4);  // 8 MB
    if (ws_size >= need32) {
        dmmse_k1<32><<<B * 32 / K1_WPB, K1_BLK, 0, stream>>>(data, targets, W, part);
        dmmse_k2<<<(B * N) / 256, 256, 0, stream>>>(part, out, 32);
    } else {
        // fallback proven in round 6 (needs 4 MB)
        dmmse_k1<16><<<B * 16 / K1_WPB, K1_BLK, 0, stream>>>(data, targets, W, part);
        dmmse_k2<<<(B * N) / 256, 256, 0, stream>>>(part, out, 16);
    }
}

// Round 9
// 402.329 us; speedup vs baseline: 1.1664x; 1.1664x over previous
//
#include <hip/hip_runtime.h>

// DiscreteMMSE, round 9: NCHUNK=32 + launch_bounds(256,2) (VGPR cap 128).
//
//   data   : [B=128][N=128][D=64] f32
//   targets: [B=128][N=128]       f32
//   W      : [D=64][T=4096]       f32
//   out    : [B=128][N=128]       f32
//
// Empirical hipcc rule from r3-r8 counters: VGPR cap ~= 256/arg2 of
// __launch_bounds__.  (256,4) -> cap 64 -> r8 spilled (44 MB scratch writes).
// (256,2) -> cap 128 -> r6 ran clean at VGPR=120.  Runtime residency is
// VGPR-determined, NOT arg2-determined: at VGPR<=128 the HW can host
// 4 waves/SIMD, and the NCHUNK=32 grid (4096 waves = 16/CU) provides them.
//
// K1: one WAVE per (batch, 128-col chunk): 4096 independent waves, no
//     barriers, no LDS. Per step n emits (m_ref, s, p) over its 128 cols
//     (2/lane); m_ref = exact chunk max of csum_{n-1} from the previous
//     step's fused in-wave DPP reduce. csum starts 0, decreases -> exp2
//     args <= 0; n=0 falls out (e=1 -> chunk mean).
// K2: per (b,n) online associative softmax combine over chunk partials,
//     layout part[chunk][b*N+n] -> lane-coalesced.
//
// ws: NCHUNK=32 needs 8 MB; guarded fallback to r6's proven NCHUNK=16 (4 MB).

#define B 128
#define N 128
#define D 64
#define T 4096
#define NT 16
#define NTILES (N / NT)
#define K1_BLK 256
#define K1_WPB (K1_BLK / 64)

// DPP ctrl codes
#define DPP_XOR1 0xB1    // quad_perm(1,0,3,2)
#define DPP_XOR2 0x4E    // quad_perm(2,3,0,1)
#define DPP_XOR4 0x141   // row_half_mirror
#define DPP_XOR8 0x140   // row_mirror

template <int CTRL>
__device__ __forceinline__ float dppf(float x) {
    return __int_as_float(
        __builtin_amdgcn_mov_dpp(__float_as_int(x), CTRL, 0xF, 0xF, true));
}

// full-wave (64-lane) reduce of (m:max, s:sum, p:sum); result in all lanes
__device__ __forceinline__ void wave_red3(float& m, float& s, float& p) {
    m = fmaxf(m, dppf<DPP_XOR1>(m)); s += dppf<DPP_XOR1>(s); p += dppf<DPP_XOR1>(p);
    m = fmaxf(m, dppf<DPP_XOR2>(m)); s += dppf<DPP_XOR2>(s); p += dppf<DPP_XOR2>(p);
    m = fmaxf(m, dppf<DPP_XOR4>(m)); s += dppf<DPP_XOR4>(s); p += dppf<DPP_XOR4>(p);
    m = fmaxf(m, dppf<DPP_XOR8>(m)); s += dppf<DPP_XOR8>(s); p += dppf<DPP_XOR8>(p);
    m = fmaxf(m, __shfl_xor(m, 16, 64)); s += __shfl_xor(s, 16, 64); p += __shfl_xor(p, 16, 64);
    m = fmaxf(m, __shfl_xor(m, 32, 64)); s += __shfl_xor(s, 32, 64); p += __shfl_xor(p, 32, 64);
}

// ---------------- primary: NCHUNK=32, 2 cols/lane ----------------
__global__ __launch_bounds__(K1_BLK, 2)
void dmmse_k1_c32(const float* __restrict__ data,
                  const float* __restrict__ targets,
                  const float* __restrict__ W,
                  float4* __restrict__ part)      // [32][B*N] (m, s, p, _)
{
    const int tid   = threadIdx.x;
    const int lane  = tid & 63;
    const int g     = blockIdx.x * K1_WPB + (tid >> 6);
    const int b     = g >> 5;
    const int chunk = g & 31;

    const float2* W2   = reinterpret_cast<const float2*>(W);  // [D][T/2]
    const int     wcol = chunk * 64 + lane;                   // float2 col index

    const float KHL2E = -0.5f * 1.44269504088896340736f;  // -0.5*log2(e)

    float csum0 = 0.f, csum1 = 0.f;
    float M = 0.f;    // chunk max of csum_{n-1}; 0 at n==0

    for (int j = 0; j < NTILES; ++j) {
        float mu[NT][2];
        #pragma unroll
        for (int i = 0; i < NT; ++i) { mu[i][0] = 0.f; mu[i][1] = 0.f; }

        const float* drow = data + (b * N + j * NT) * D;   // lane-uniform base

#define FMA_GROUP(dc_, wv0, wv1, wv2, wv3)                                     \
        _Pragma("unroll")                                                      \
        for (int i = 0; i < NT; ++i) {                                         \
            const float4 x = *reinterpret_cast<const float4*>(drow + i * D + (dc_)); \
            mu[i][0] = fmaf(x.x, wv0.x, mu[i][0]);                             \
            mu[i][1] = fmaf(x.x, wv0.y, mu[i][1]);                             \
            mu[i][0] = fmaf(x.y, wv1.x, mu[i][0]);                             \
            mu[i][1] = fmaf(x.y, wv1.y, mu[i][1]);                             \
            mu[i][0] = fmaf(x.z, wv2.x, mu[i][0]);                             \
            mu[i][1] = fmaf(x.z, wv2.y, mu[i][1]);                             \
            mu[i][0] = fmaf(x.w, wv3.x, mu[i][0]);                             \
            mu[i][1] = fmaf(x.w, wv3.y, mu[i][1]);                             \
        }

        float2 a0 = W2[0 * (T / 2) + wcol];
        float2 a1 = W2[1 * (T / 2) + wcol];
        float2 a2 = W2[2 * (T / 2) + wcol];
        float2 a3 = W2[3 * (T / 2) + wcol];
        for (int dc = 0; dc < D - 4; dc += 4) {
            const float2 b0 = W2[(dc + 4) * (T / 2) + wcol];
            const float2 b1 = W2[(dc + 5) * (T / 2) + wcol];
            const float2 b2 = W2[(dc + 6) * (T / 2) + wcol];
            const float2 b3 = W2[(dc + 7) * (T / 2) + wcol];
            FMA_GROUP(dc, a0, a1, a2, a3)
            a0 = b0; a1 = b1; a2 = b2; a3 = b3;
        }
        FMA_GROUP(D - 4, a0, a1, a2, a3)
#undef FMA_GROUP

        #pragma unroll
        for (int i = 0; i < NT; ++i) {
            const int n = j * NT + i;

            const float e0 = exp2f(csum0 - M);
            const float e1 = exp2f(csum1 - M);
            float s = e0 + e1;
            float p = e0 * mu[i][0] + e1 * mu[i][1];

            if (n < N - 1) {
                const float y = targets[b * N + n];   // lane-uniform -> s_load
                float e;
                e = y - mu[i][0]; csum0 = fmaf(KHL2E * e, e, csum0);
                e = y - mu[i][1]; csum1 = fmaf(KHL2E * e, e, csum1);
            }
            float m = fmaxf(csum0, csum1);

            wave_red3(m, s, p);
            if (lane == 0)
                part[chunk * (B * N) + b * N + n] = make_float4(M, s, p, 0.f);
            M = m;
        }
    }
}

// ---------------- fallback: NCHUNK=16, 4 cols/lane (r6 proven) ----------------
__global__ __launch_bounds__(K1_BLK, 2)
void dmmse_k1_c16(const float* __restrict__ data,
                  const float* __restrict__ targets,
                  const float* __restrict__ W,
                  float4* __restrict__ part)      // [16][B*N] (m, s, p, _)
{
    const int tid   = threadIdx.x;
    const int lane  = tid & 63;
    const int g     = blockIdx.x * K1_WPB + (tid >> 6);
    const int b     = g >> 4;
    const int chunk = g & 15;

    const float4* W4   = reinterpret_cast<const float4*>(W);  // [D][T/4]
    const int     wcol = chunk * 64 + lane;                   // float4 col index

    const float KHL2E = -0.5f * 1.44269504088896340736f;

    float csum0 = 0.f, csum1 = 0.f, csum2 = 0.f, csum3 = 0.f;
    float M = 0.f;

    for (int j = 0; j < NTILES; ++j) {
        float mu[NT][4];
        #pragma unroll
        for (int i = 0; i < NT; ++i) { mu[i][0]=0.f; mu[i][1]=0.f; mu[i][2]=0.f; mu[i][3]=0.f; }

        const float* drow = data + (b * N + j * NT) * D;

#define FMA_GROUP(dc_, wv0, wv1, wv2, wv3)                                     \
        _Pragma("unroll")                                                      \
        for (int i = 0; i < NT; ++i) {                                         \
            const float4 x = *reinterpret_cast<const float4*>(drow + i * D + (dc_)); \
            mu[i][0] = fmaf(x.x, wv0.x, mu[i][0]);                             \
            mu[i][1] = fmaf(x.x, wv0.y, mu[i][1]);                             \
            mu[i][2] = fmaf(x.x, wv0.z, mu[i][2]);                             \
            mu[i][3] = fmaf(x.x, wv0.w, mu[i][3]);                             \
            mu[i][0] = fmaf(x.y, wv1.x, mu[i][0]);                             \
            mu[i][1] = fmaf(x.y, wv1.y, mu[i][1]);                             \
            mu[i][2] = fmaf(x.y, wv1.z, mu[i][2]);                             \
            mu[i][3] = fmaf(x.y, wv1.w, mu[i][3]);                             \
            mu[i][0] = fmaf(x.z, wv2.x, mu[i][0]);                             \
            mu[i][1] = fmaf(x.z, wv2.y, mu[i][1]);                             \
            mu[i][2] = fmaf(x.z, wv2.z, mu[i][2]);                             \
            mu[i][3] = fmaf(x.z, wv2.w, mu[i][3]);                             \
            mu[i][0] = fmaf(x.w, wv3.x, mu[i][0]);                             \
            mu[i][1] = fmaf(x.w, wv3.y, mu[i][1]);                             \
            mu[i][2] = fmaf(x.w, wv3.z, mu[i][2]);                             \
            mu[i][3] = fmaf(x.w, wv3.w, mu[i][3]);                             \
        }

        float4 a0 = W4[0 * (T / 4) + wcol];
        float4 a1 = W4[1 * (T / 4) + wcol];
        float4 a2 = W4[2 * (T / 4) + wcol];
        float4 a3 = W4[3 * (T / 4) + wcol];
        for (int dc = 0; dc < D - 4; dc += 4) {
            const float4 b0 = W4[(dc + 4) * (T / 4) + wcol];
            const float4 b1 = W4[(dc + 5) * (T / 4) + wcol];
            const float4 b2 = W4[(dc + 6) * (T / 4) + wcol];
            const float4 b3 = W4[(dc + 7) * (T / 4) + wcol];
            FMA_GROUP(dc, a0, a1, a2, a3)
            a0 = b0; a1 = b1; a2 = b2; a3 = b3;
        }
        FMA_GROUP(D - 4, a0, a1, a2, a3)
#undef FMA_GROUP

        #pragma unroll
        for (int i = 0; i < NT; ++i) {
            const int n = j * NT + i;

            const float e0 = exp2f(csum0 - M);
            const float e1 = exp2f(csum1 - M);
            const float e2 = exp2f(csum2 - M);
            const float e3 = exp2f(csum3 - M);
            float s = e0 + e1 + e2 + e3;
            float p = e0 * mu[i][0] + e1 * mu[i][1] + e2 * mu[i][2] + e3 * mu[i][3];

            if (n < N - 1) {
                const float y = targets[b * N + n];
                float e;
                e = y - mu[i][0]; csum0 = fmaf(KHL2E * e, e, csum0);
                e = y - mu[i][1]; csum1 = fmaf(KHL2E * e, e, csum1);
                e = y - mu[i][2]; csum2 = fmaf(KHL2E * e, e, csum2);
                e = y - mu[i][3]; csum3 = fmaf(KHL2E * e, e, csum3);
            }
            float m = fmaxf(fmaxf(csum0, csum1), fmaxf(csum2, csum3));

            wave_red3(m, s, p);
            if (lane == 0)
                part[chunk * (B * N) + b * N + n] = make_float4(M, s, p, 0.f);
            M = m;
        }
    }
}

__global__ __launch_bounds__(256)
void dmmse_k2(const float4* __restrict__ part,   // [nchunk][B*N]
              float* __restrict__ out,           // [B*N]
              int nchunk)
{
    const int t = blockIdx.x * 256 + threadIdx.x;

    float M = -__builtin_inff(), S = 0.f, P = 0.f;
    for (int c = 0; c < nchunk; ++c) {
        const float4 v = part[c * (B * N) + t];     // lane-coalesced
        const float nM = fmaxf(M, v.x);
        const float aa = exp2f(M - nM);
        const float f  = exp2f(v.x - nM);
        S = S * aa + v.y * f;
        P = P * aa + v.z * f;
        M = nM;
    }
    out[t] = P / S;
}

extern "C" void kernel_launch(void* const* d_in, const int* in_sizes, int n_in,
                              void* d_out, int out_size, void* d_ws, size_t ws_size,
                              hipStream_t stream)
{
    const float* data    = (const float*)d_in[0];   // 128*128*64
    const float* targets = (const float*)d_in[1];   // 128*128
    const float* W       = (const float*)d_in[2];   // 64*4096
    float* out           = (float*)d_out;           // 128*128
    float4* part         = (float4*)d_ws;

    const size_t need32 = (size_t)32 * B * N * sizeof(float4);  // 8 MB
    if (ws_size >= need32) {
        dmmse_k1_c32<<<B * 32 / K1_WPB, K1_BLK, 0, stream>>>(data, targets, W, part);
        dmmse_k2<<<(B * N) / 256, 256, 0, stream>>>(part, out, 32);
    } else {
        dmmse_k1_c16<<<B * 16 / K1_WPB, K1_BLK, 0, stream>>>(data, targets, W, part);
        dmmse_k2<<<(B * N) / 256, 256, 0, stream>>>(part, out, 16);
    }
}

// Round 10
// 257.793 us; speedup vs baseline: 1.8204x; 1.5607x over previous
//
#include <hip/hip_runtime.h>

// DiscreteMMSE, round 10: r6 shape (NCHUNK=16, CPL=4) + off-chain reduction.
//
//   data   : [B=128][N=128][D=64] f32
//   targets: [B=128][N=128]       f32
//   W      : [D=64][T=4096]       f32
//   out    : [B=128][N=128]       f32
//
// r9 post-mortem: CPL=2 halves FMAs/load + ILP, doubles fixed costs ->
// 372us regression. Back to CPL=4. New target: the per-step SERIAL chain
// through the wave reduce (6 DS-pipe shfl, ~300-400cy latency x 128 steps,
// unhidden at 2 waves/SIMD).
//
// Scheme: per 16-lane group (64 cols), keep reference M_g = group max of
// csum_{n-1}, maintained by a pure-DPP max tree (VALU, ~10cy serial) -- the
// ONLY value on the step-to-step chain. s,p are group-summed by DPP-only
// add trees; the 4 group triples (M_g,S_g,P_g) are merged to a wave triple
// by the associative softmax combine (2 shfl levels + rescale) -- pure
// dataflow into lane0's store, OFF the chain. Exact math: group max is a
// valid softmax reference; combine rescales exactly. K2 unchanged.
//
// ws: 16 * B*N * 16B = 4 MB (proven in r6).

#define B 128
#define N 128
#define D 64
#define T 4096
#define NT 16
#define NTILES (N / NT)
#define NCHUNK 16
#define K1_BLK 256
#define K1_WPB (K1_BLK / 64)
#define K1_GRID (B * NCHUNK / K1_WPB)   // 512 blocks

// DPP ctrl codes
#define DPP_XOR1 0xB1    // quad_perm(1,0,3,2)
#define DPP_XOR2 0x4E    // quad_perm(2,3,0,1)
#define DPP_XOR4 0x141   // row_half_mirror
#define DPP_XOR8 0x140   // row_mirror

template <int CTRL>
__device__ __forceinline__ float dppf(float x) {
    return __int_as_float(
        __builtin_amdgcn_mov_dpp(__float_as_int(x), CTRL, 0xF, 0xF, true));
}

// 16-lane-group max tree (all lanes of each group get the result). VALU-only.
__device__ __forceinline__ float dpp_max16(float m) {
    m = fmaxf(m, dppf<DPP_XOR1>(m));
    m = fmaxf(m, dppf<DPP_XOR2>(m));
    m = fmaxf(m, dppf<DPP_XOR4>(m));
    m = fmaxf(m, dppf<DPP_XOR8>(m));
    return m;
}

// 16-lane-group sum tree. VALU-only.
__device__ __forceinline__ float dpp_sum16(float s) {
    s += dppf<DPP_XOR1>(s);
    s += dppf<DPP_XOR2>(s);
    s += dppf<DPP_XOR4>(s);
    s += dppf<DPP_XOR8>(s);
    return s;
}

__global__ __launch_bounds__(K1_BLK, 2)
void dmmse_k1(const float* __restrict__ data,
              const float* __restrict__ targets,
              const float* __restrict__ W,
              float4* __restrict__ part)      // [NCHUNK][B*N] (m, s, p, _)
{
    const int tid   = threadIdx.x;
    const int lane  = tid & 63;
    const int g     = blockIdx.x * K1_WPB + (tid >> 6);
    const int b     = g >> 4;
    const int chunk = g & 15;

    const float4* W4   = reinterpret_cast<const float4*>(W);  // [D][T/4]
    const int     wcol = chunk * 64 + lane;                   // float4 col index

    const float KHL2E = -0.5f * 1.44269504088896340736f;      // -0.5*log2(e)

    float csum0 = 0.f, csum1 = 0.f, csum2 = 0.f, csum3 = 0.f;
    float Mg = 0.f;   // group (16-lane, 64-col) max of csum_{n-1}; 0 at n==0

    for (int j = 0; j < NTILES; ++j) {
        // ---- mu[i][c] = data[n_i] . W[:, 4*wcol+c] ----
        float mu[NT][4];
        #pragma unroll
        for (int i = 0; i < NT; ++i) { mu[i][0]=0.f; mu[i][1]=0.f; mu[i][2]=0.f; mu[i][3]=0.f; }

        const float* drow = data + (b * N + j * NT) * D;   // lane-uniform base

#define FMA_GROUP(dc_, wv0, wv1, wv2, wv3)                                     \
        _Pragma("unroll")                                                      \
        for (int i = 0; i < NT; ++i) {                                         \
            const float4 x = *reinterpret_cast<const float4*>(drow + i * D + (dc_)); \
            mu[i][0] = fmaf(x.x, wv0.x, mu[i][0]);                             \
            mu[i][1] = fmaf(x.x, wv0.y, mu[i][1]);                             \
            mu[i][2] = fmaf(x.x, wv0.z, mu[i][2]);                             \
            mu[i][3] = fmaf(x.x, wv0.w, mu[i][3]);                             \
            mu[i][0] = fmaf(x.y, wv1.x, mu[i][0]);                             \
            mu[i][1] = fmaf(x.y, wv1.y, mu[i][1]);                             \
            mu[i][2] = fmaf(x.y, wv1.z, mu[i][2]);                             \
            mu[i][3] = fmaf(x.y, wv1.w, mu[i][3]);                             \
            mu[i][0] = fmaf(x.z, wv2.x, mu[i][0]);                             \
            mu[i][1] = fmaf(x.z, wv2.y, mu[i][1]);                             \
            mu[i][2] = fmaf(x.z, wv2.z, mu[i][2]);                             \
            mu[i][3] = fmaf(x.z, wv2.w, mu[i][3]);                             \
            mu[i][0] = fmaf(x.w, wv3.x, mu[i][0]);                             \
            mu[i][1] = fmaf(x.w, wv3.y, mu[i][1]);                             \
            mu[i][2] = fmaf(x.w, wv3.z, mu[i][2]);                             \
            mu[i][3] = fmaf(x.w, wv3.w, mu[i][3]);                             \
        }

        // register double-buffered W stream: load group dc+4 while FMAing dc
        float4 a0 = W4[0 * (T / 4) + wcol];
        float4 a1 = W4[1 * (T / 4) + wcol];
        float4 a2 = W4[2 * (T / 4) + wcol];
        float4 a3 = W4[3 * (T / 4) + wcol];
        for (int dc = 0; dc < D - 4; dc += 4) {
            const float4 b0 = W4[(dc + 4) * (T / 4) + wcol];
            const float4 b1 = W4[(dc + 5) * (T / 4) + wcol];
            const float4 b2 = W4[(dc + 6) * (T / 4) + wcol];
            const float4 b3 = W4[(dc + 7) * (T / 4) + wcol];
            FMA_GROUP(dc, a0, a1, a2, a3)
            a0 = b0; a1 = b1; a2 = b2; a3 = b3;
        }
        FMA_GROUP(D - 4, a0, a1, a2, a3)
#undef FMA_GROUP

        // ---- sequential softmax steps: DPP-only on the serial chain ----
        #pragma unroll
        for (int i = 0; i < NT; ++i) {
            const int n = j * NT + i;

            // weights vs csum_{n-1}, group-local reference Mg (exact max)
            const float e0 = exp2f(csum0 - Mg);
            const float e1 = exp2f(csum1 - Mg);
            const float e2 = exp2f(csum2 - Mg);
            const float e3 = exp2f(csum3 - Mg);
            float s = (e0 + e1) + (e2 + e3);
            float p = fmaf(e0, mu[i][0],
                      fmaf(e1, mu[i][1],
                      fmaf(e2, mu[i][2], e3 * mu[i][3])));

            // group sums (off the step-to-step chain)
            s = dpp_sum16(s);
            p = dpp_sum16(p);

            // wave combine of the 4 group triples: associative softmax merge.
            // Off-chain: result feeds only the store.
            float mw = Mg, sw = s, pw = p;
            {
                const float mx = __shfl_xor(mw, 16, 64);
                const float sx = __shfl_xor(sw, 16, 64);
                const float px = __shfl_xor(pw, 16, 64);
                const float mn = fmaxf(mw, mx);
                const float fa = exp2f(mw - mn);
                const float fb = exp2f(mx - mn);
                sw = fmaf(sw, fa, sx * fb);
                pw = fmaf(pw, fa, px * fb);
                mw = mn;
            }
            {
                const float mx = __shfl_xor(mw, 32, 64);
                const float sx = __shfl_xor(sw, 32, 64);
                const float px = __shfl_xor(pw, 32, 64);
                const float mn = fmaxf(mw, mx);
                const float fa = exp2f(mw - mn);
                const float fb = exp2f(mx - mn);
                sw = fmaf(sw, fa, sx * fb);
                pw = fmaf(pw, fa, px * fb);
                mw = mn;
            }
            if (lane == 0)
                part[chunk * (B * N) + b * N + n] = make_float4(mw, sw, pw, 0.f);

            // csum update (t-uniform constants dropped), then next group ref:
            // local max4 + 4 DPP levels -- the ONLY serial carry to step n+1.
            if (n < N - 1) {
                const float y = targets[b * N + n];   // lane-uniform -> s_load
                float e;
                e = y - mu[i][0]; csum0 = fmaf(KHL2E * e, e, csum0);
                e = y - mu[i][1]; csum1 = fmaf(KHL2E * e, e, csum1);
                e = y - mu[i][2]; csum2 = fmaf(KHL2E * e, e, csum2);
                e = y - mu[i][3]; csum3 = fmaf(KHL2E * e, e, csum3);
            }
            Mg = dpp_max16(fmaxf(fmaxf(csum0, csum1), fmaxf(csum2, csum3)));
        }
    }
}

__global__ __launch_bounds__(256)
void dmmse_k2(const float4* __restrict__ part,   // [NCHUNK][B*N]
              float* __restrict__ out)           // [B*N]
{
    const int t = blockIdx.x * 256 + threadIdx.x;

    // online associative softmax combine over chunk partials
    float M = -__builtin_inff(), S = 0.f, P = 0.f;
    #pragma unroll
    for (int c = 0; c < NCHUNK; ++c) {
        const float4 v = part[c * (B * N) + t];     // lane-coalesced
        const float nM = fmaxf(M, v.x);
        const float aa = exp2f(M - nM);
        const float f  = exp2f(v.x - nM);
        S = S * aa + v.y * f;
        P = P * aa + v.z * f;
        M = nM;
    }
    out[t] = P / S;
}

extern "C" void kernel_launch(void* const* d_in, const int* in_sizes, int n_in,
                              void* d_out, int out_size, void* d_ws, size_t ws_size,
                              hipStream_t stream)
{
    const float* data    = (const float*)d_in[0];   // 128*128*64
    const float* targets = (const float*)d_in[1];   // 128*128
    const float* W       = (const float*)d_in[2];   // 64*4096
    float* out           = (float*)d_out;           // 128*128
    float4* part         = (float4*)d_ws;           // 4 MB partials (proven)

    dmmse_k1<<<K1_GRID, K1_BLK, 0, stream>>>(data, targets, W, part);
    dmmse_k2<<<(B * N) / 256, 256, 0, stream>>>(part, out);
}

// Round 14
// 245.926 us; speedup vs baseline: 1.9083x; 1.0483x over previous
//
#include <hip/hip_runtime.h>

// DiscreteMMSE, round 14 (r11-r13 gave no bench signal; r1->r2 proved the
// "container failed twice" mode is infra-flake on identical code).
// r10 structure; softmax exp path reverted to ln-units + __expf — the exact
// numeric path that RAN AND PASSED in r3/r4. Zero unproven ingredients.
//
//   data   : [B=128][N=128][D=64] f32
//   targets: [B=128][N=128]       f32
//   W      : [D=64][T=4096]       f32
//   out    : [B=128][N=128]       f32
//
// Theory under test (from r10-vs-r6 differential): libm exp2f lowers to the
// precise __ocml_exp2_f32 (~40cyc/call, 8 calls/step ~ 320 of the ~570
// cyc/step measured); __expf is the native v_mul+v_exp_f32 path (~2 ops).
//
// Structure recap: K1 = one wave per (batch, 256-col chunk), NCHUNK=16,
// CPL=4, no barriers/LDS. Per-16-lane-group reference max Mg on the serial
// chain (pure-DPP max tree); group (s,p) DPP sums + associative wave
// combine off the chain; (m,s,p) partial per (b,n,chunk) to d_ws (4 MB,
// proven). K2 = online associative softmax combine over 16 chunk partials.

#define B 128
#define N 128
#define D 64
#define T 4096
#define NT 16
#define NTILES (N / NT)
#define NCHUNK 16
#define K1_BLK 256
#define K1_WPB (K1_BLK / 64)
#define K1_GRID (B * NCHUNK / K1_WPB)   // 512 blocks

// DPP ctrl codes
#define DPP_XOR1 0xB1    // quad_perm(1,0,3,2)
#define DPP_XOR2 0x4E    // quad_perm(2,3,0,1)
#define DPP_XOR4 0x141   // row_half_mirror
#define DPP_XOR8 0x140   // row_mirror

template <int CTRL>
__device__ __forceinline__ float dppf(float x) {
    return __int_as_float(
        __builtin_amdgcn_mov_dpp(__float_as_int(x), CTRL, 0xF, 0xF, true));
}

// 16-lane-group max tree (all lanes of each group get the result). VALU-only.
__device__ __forceinline__ float dpp_max16(float m) {
    m = fmaxf(m, dppf<DPP_XOR1>(m));
    m = fmaxf(m, dppf<DPP_XOR2>(m));
    m = fmaxf(m, dppf<DPP_XOR4>(m));
    m = fmaxf(m, dppf<DPP_XOR8>(m));
    return m;
}

// 16-lane-group sum tree. VALU-only.
__device__ __forceinline__ float dpp_sum16(float s) {
    s += dppf<DPP_XOR1>(s);
    s += dppf<DPP_XOR2>(s);
    s += dppf<DPP_XOR4>(s);
    s += dppf<DPP_XOR8>(s);
    return s;
}

__global__ __launch_bounds__(K1_BLK, 2)
void dmmse_k1(const float* __restrict__ data,
              const float* __restrict__ targets,
              const float* __restrict__ W,
              float4* __restrict__ part)      // [NCHUNK][B*N] (m, s, p, _)
{
    const int tid   = threadIdx.x;
    const int lane  = tid & 63;
    const int g     = blockIdx.x * K1_WPB + (tid >> 6);
    const int b     = g >> 4;
    const int chunk = g & 15;

    const float4* W4   = reinterpret_cast<const float4*>(W);  // [D][T/4]
    const int     wcol = chunk * 64 + lane;                   // float4 col index

    // csum in natural-log units (exactly r4's formula): csum += -0.5*(y-mu)^2
    float csum0 = 0.f, csum1 = 0.f, csum2 = 0.f, csum3 = 0.f;
    float Mg = 0.f;   // group (16-lane, 64-col) max of csum_{n-1}; 0 at n==0

    for (int j = 0; j < NTILES; ++j) {
        // ---- mu[i][c] = data[n_i] . W[:, 4*wcol+c] ----
        float mu[NT][4];
        #pragma unroll
        for (int i = 0; i < NT; ++i) { mu[i][0]=0.f; mu[i][1]=0.f; mu[i][2]=0.f; mu[i][3]=0.f; }

        const float* drow = data + (b * N + j * NT) * D;   // lane-uniform base

#define FMA_GROUP(dc_, wv0, wv1, wv2, wv3)                                     \
        _Pragma("unroll")                                                      \
        for (int i = 0; i < NT; ++i) {                                         \
            const float4 x = *reinterpret_cast<const float4*>(drow + i * D + (dc_)); \
            mu[i][0] = fmaf(x.x, wv0.x, mu[i][0]);                             \
            mu[i][1] = fmaf(x.x, wv0.y, mu[i][1]);                             \
            mu[i][2] = fmaf(x.x, wv0.z, mu[i][2]);                             \
            mu[i][3] = fmaf(x.x, wv0.w, mu[i][3]);                             \
            mu[i][0] = fmaf(x.y, wv1.x, mu[i][0]);                             \
            mu[i][1] = fmaf(x.y, wv1.y, mu[i][1]);                             \
            mu[i][2] = fmaf(x.y, wv1.z, mu[i][2]);                             \
            mu[i][3] = fmaf(x.y, wv1.w, mu[i][3]);                             \
            mu[i][0] = fmaf(x.z, wv2.x, mu[i][0]);                             \
            mu[i][1] = fmaf(x.z, wv2.y, mu[i][1]);                             \
            mu[i][2] = fmaf(x.z, wv2.z, mu[i][2]);                             \
            mu[i][3] = fmaf(x.z, wv2.w, mu[i][3]);                             \
            mu[i][0] = fmaf(x.w, wv3.x, mu[i][0]);                             \
            mu[i][1] = fmaf(x.w, wv3.y, mu[i][1]);                             \
            mu[i][2] = fmaf(x.w, wv3.z, mu[i][2]);                             \
            mu[i][3] = fmaf(x.w, wv3.w, mu[i][3]);                             \
        }

        // register double-buffered W stream: load group dc+4 while FMAing dc
        float4 a0 = W4[0 * (T / 4) + wcol];
        float4 a1 = W4[1 * (T / 4) + wcol];
        float4 a2 = W4[2 * (T / 4) + wcol];
        float4 a3 = W4[3 * (T / 4) + wcol];
        for (int dc = 0; dc < D - 4; dc += 4) {
            const float4 b0 = W4[(dc + 4) * (T / 4) + wcol];
            const float4 b1 = W4[(dc + 5) * (T / 4) + wcol];
            const float4 b2 = W4[(dc + 6) * (T / 4) + wcol];
            const float4 b3 = W4[(dc + 7) * (T / 4) + wcol];
            FMA_GROUP(dc, a0, a1, a2, a3)
            a0 = b0; a1 = b1; a2 = b2; a3 = b3;
        }
        FMA_GROUP(D - 4, a0, a1, a2, a3)
#undef FMA_GROUP

        // ---- sequential softmax steps: DPP-only on the serial chain ----
        #pragma unroll
        for (int i = 0; i < NT; ++i) {
            const int n = j * NT + i;

            // weights vs csum_{n-1}, group-local reference Mg (exact max)
            const float e0 = __expf(csum0 - Mg);
            const float e1 = __expf(csum1 - Mg);
            const float e2 = __expf(csum2 - Mg);
            const float e3 = __expf(csum3 - Mg);
            float s = (e0 + e1) + (e2 + e3);
            float p = fmaf(e0, mu[i][0],
                      fmaf(e1, mu[i][1],
                      fmaf(e2, mu[i][2], e3 * mu[i][3])));

            // group sums (off the step-to-step chain)
            s = dpp_sum16(s);
            p = dpp_sum16(p);

            // wave combine of the 4 group triples: associative softmax merge.
            // Off-chain: result feeds only the store.
            float mw = Mg, sw = s, pw = p;
            {
                const float mx = __shfl_xor(mw, 16, 64);
                const float sx = __shfl_xor(sw, 16, 64);
                const float px = __shfl_xor(pw, 16, 64);
                const float mn = fmaxf(mw, mx);
                const float fa = __expf(mw - mn);
                const float fb = __expf(mx - mn);
                sw = fmaf(sw, fa, sx * fb);
                pw = fmaf(pw, fa, px * fb);
                mw = mn;
            }
            {
                const float mx = __shfl_xor(mw, 32, 64);
                const float sx = __shfl_xor(sw, 32, 64);
                const float px = __shfl_xor(pw, 32, 64);
                const float mn = fmaxf(mw, mx);
                const float fa = __expf(mw - mn);
                const float fb = __expf(mx - mn);
                sw = fmaf(sw, fa, sx * fb);
                pw = fmaf(pw, fa, px * fb);
                mw = mn;
            }
            if (lane == 0)
                part[chunk * (B * N) + b * N + n] = make_float4(mw, sw, pw, 0.f);

            // csum update (t-uniform constants dropped), then next group ref:
            // local max4 + DPP max tree -- the ONLY serial carry to step n+1.
            if (n < N - 1) {
                const float y = targets[b * N + n];   // lane-uniform -> s_load
                float e;
                e = y - mu[i][0]; csum0 = fmaf(-0.5f * e, e, csum0);
                e = y - mu[i][1]; csum1 = fmaf(-0.5f * e, e, csum1);
                e = y - mu[i][2]; csum2 = fmaf(-0.5f * e, e, csum2);
                e = y - mu[i][3]; csum3 = fmaf(-0.5f * e, e, csum3);
            }
            Mg = dpp_max16(fmaxf(fmaxf(csum0, csum1), fmaxf(csum2, csum3)));
        }
    }
}

__global__ __launch_bounds__(256)
void dmmse_k2(const float4* __restrict__ part,   // [NCHUNK][B*N]
              float* __restrict__ out)           // [B*N]
{
    const int t = blockIdx.x * 256 + threadIdx.x;

    // online associative softmax combine over chunk partials
    float M = -__builtin_inff(), S = 0.f, P = 0.f;
    #pragma unroll
    for (int c = 0; c < NCHUNK; ++c) {
        const float4 v = part[c * (B * N) + t];     // lane-coalesced
        const float nM = fmaxf(M, v.x);
        const float aa = __expf(M - nM);
        const float f  = __expf(v.x - nM);
        S = S * aa + v.y * f;
        P = P * aa + v.z * f;
        M = nM;
    }
    out[t] = P / S;
}

extern "C" void kernel_launch(void* const* d_in, const int* in_sizes, int n_in,
                              void* d_out, int out_size, void* d_ws, size_t ws_size,
                              hipStream_t stream)
{
    const float* data    = (const float*)d_in[0];   // 128*128*64
    const float* targets = (const float*)d_in[1];   // 128*128
    const float* W       = (const float*)d_in[2];   // 64*4096
    float* out           = (float*)d_out;           // 128*128
    float4* part         = (float4*)d_ws;           // 4 MB partials (proven)

    dmmse_k1<<<K1_GRID, K1_BLK, 0, stream>>>(data, targets, W, part);
    dmmse_k2<<<(B * N) / 256, 256, 0, stream>>>(part, out);
}